// Round 4
// baseline (129.004 us; speedup 1.0000x reference)
//
#include <hip/hip_runtime.h>
#include <hip/hip_bf16.h>

#define B_ 16
#define T_ 32
#define NS_ 10
#define D_ 128
#define ST_ 512
#define V_ 32000
#define NCHAIN 160

using short8  = __attribute__((ext_vector_type(8))) short;
using f32x4   = __attribute__((ext_vector_type(4))) float;
using uintx16 = __attribute__((ext_vector_type(16))) unsigned;
using half2v  = __attribute__((ext_vector_type(2))) _Float16;

__device__ __forceinline__ unsigned short f2bf(float f){
  unsigned u = __float_as_uint(f);
  u += 0x7FFFu + ((u >> 16) & 1u);          // RNE to bf16
  return (unsigned short)(u >> 16);
}
__device__ __forceinline__ unsigned packbf(float a, float b){
  return ((unsigned)f2bf(b) << 16) | (unsigned)f2bf(a);
}
__device__ __forceinline__ unsigned packh(float a, float b){
  unsigned short ua = __builtin_bit_cast(unsigned short, (_Float16)a);
  unsigned short ub = __builtin_bit_cast(unsigned short, (_Float16)b);
  return ((unsigned)ub << 16) | ua;
}
__device__ __forceinline__ half2v u2h2(unsigned u){
  return __builtin_bit_cast(half2v, u);
}
__device__ __forceinline__ void mach2(unsigned ux, unsigned ul, unsigned uh,
                                      float& a1, float& a2){
#if __has_builtin(__builtin_amdgcn_fdot2)
  a1 = __builtin_amdgcn_fdot2(u2h2(ux), u2h2(ul), a1, false);
  a2 = __builtin_amdgcn_fdot2(u2h2(ux), u2h2(uh), a2, false);
#else
  half2v x = u2h2(ux), l = u2h2(ul), h = u2h2(uh);
  a1 += (float)x[0]*(float)l[0] + (float)x[1]*(float)l[1];
  a2 += (float)x[0]*(float)h[0] + (float)x[1]*(float)h[1];
#endif
}

// ---------------------------------------------------------------------------
// Phase B: partial[s] = sum_v exp(move_s . vocabW_v + vb_v)   (512x32000 GEMM)
// ---------------------------------------------------------------------------
__global__ __launch_bounds__(256) void logz_kernel(
    const float* __restrict__ move, const float* __restrict__ vw,
    const float* __restrict__ vb, float* __restrict__ partial)
{
  const int sg = blockIdx.y;
  const int vc = blockIdx.x;
  const int wv = threadIdx.x >> 6;
  const int lane = threadIdx.x & 63;
  const int c16 = lane & 15, q = lane >> 4;

  __shared__ float les[64];
  if (threadIdx.x < 64) les[threadIdx.x] = 0.f;

  short8 afr[4][4];
  #pragma unroll
  for (int rt = 0; rt < 4; ++rt){
    const float* mp = move + (sg*64 + rt*16 + c16)*D_ + q*8;
    #pragma unroll
    for (int kk = 0; kk < 4; ++kk){
      float4 f0 = *(const float4*)(mp + kk*32);
      float4 f1 = *(const float4*)(mp + kk*32 + 4);
      short8 a;
      a[0]=(short)f2bf(f0.x); a[1]=(short)f2bf(f0.y);
      a[2]=(short)f2bf(f0.z); a[3]=(short)f2bf(f0.w);
      a[4]=(short)f2bf(f1.x); a[5]=(short)f2bf(f1.y);
      a[6]=(short)f2bf(f1.z); a[7]=(short)f2bf(f1.w);
      afr[rt][kk] = a;
    }
  }
  __syncthreads();

  float es[4][4] = {{0.f,0.f,0.f,0.f},{0.f,0.f,0.f,0.f},
                    {0.f,0.f,0.f,0.f},{0.f,0.f,0.f,0.f}};

  for (int it = 0; it < 4; ++it){
    const int v  = vc*256 + it*64 + wv*16 + c16;
    const float* wp = vw + v*D_ + q*8;
    short8 bfr[4];
    #pragma unroll
    for (int kk = 0; kk < 4; ++kk){
      float4 f0 = *(const float4*)(wp + kk*32);
      float4 f1 = *(const float4*)(wp + kk*32 + 4);
      short8 bb;
      bb[0]=(short)f2bf(f0.x); bb[1]=(short)f2bf(f0.y);
      bb[2]=(short)f2bf(f0.z); bb[3]=(short)f2bf(f0.w);
      bb[4]=(short)f2bf(f1.x); bb[5]=(short)f2bf(f1.y);
      bb[6]=(short)f2bf(f1.z); bb[7]=(short)f2bf(f1.w);
      bfr[kk] = bb;
    }
    const float bias = vb[v];
    #pragma unroll
    for (int rt = 0; rt < 4; ++rt){
      f32x4 acc = {0.f, 0.f, 0.f, 0.f};
      #pragma unroll
      for (int kk = 0; kk < 4; ++kk)
        acc = __builtin_amdgcn_mfma_f32_16x16x32_bf16(afr[rt][kk], bfr[kk], acc, 0, 0, 0);
      #pragma unroll
      for (int r = 0; r < 4; ++r)
        es[rt][r] += __expf(acc[r] + bias);
    }
  }
  #pragma unroll
  for (int m = 1; m < 16; m <<= 1){
    #pragma unroll
    for (int rt = 0; rt < 4; ++rt)
      #pragma unroll
      for (int r = 0; r < 4; ++r)
        es[rt][r] += __shfl_xor(es[rt][r], m, 64);
  }
  if (c16 == 0){
    #pragma unroll
    for (int rt = 0; rt < 4; ++rt)
      #pragma unroll
      for (int r = 0; r < 4; ++r)
        atomicAdd(&les[rt*16 + q*4 + r], es[rt][r]);
  }
  __syncthreads();
  if (threadIdx.x < 64) atomicAdd(&partial[sg*64 + threadIdx.x], les[threadIdx.x]);
}

// ---------------------------------------------------------------------------
// Phase A: sequential 32-step scan. One block per (b,sample) chain.
// - thread t owns W row t as f16 (j, j+64)-pairs in 8 SSA vec values (128 VGPR)
// - z carried in REGISTERS: every thread holds (z[lane], z[lane+64])
// - move staged in LDS as f16 (j, j+64)-pairs: 128 KB dynamic LDS
// - 3 barriers/step; winner thread self-identifies (cond && !cond_prev, exact)
// ---------------------------------------------------------------------------
__global__ __launch_bounds__(512) __attribute__((amdgpu_waves_per_eu(1)))
void scan_kernel(
    const int* __restrict__ zi, const float* __restrict__ latent,
    const float* __restrict__ prefW, const float* __restrict__ prefB,
    const float* __restrict__ move, const float* __restrict__ rd,
    int* __restrict__ whichOut)
{
  extern __shared__ __align__(16) char smem[];
  unsigned* xpk    = (unsigned*)smem;            // 64 u32
  float*    sTot   = (float*)(smem + 256);       // 8 f32
  int*      sWhich = (int*)(smem + 288);         // 1 int
  float*    sRd    = (float*)(smem + 292);       // 32 f32
  unsigned* mlds   = (unsigned*)(smem + 512);    // 512*64 u32 = 128 KB

  const int c = blockIdx.x, b = c / NS_, s = c % NS_;
  const int t = threadIdx.x, lane = t & 63, wv = t >> 6;

  // --- stage move into LDS as f16 pairs (j, j+64) ---
  for (int f = t; f < ST_*64; f += 512){
    const int sr = f >> 6, j = f & 63;
    mlds[f] = packh(move[sr*D_ + j], move[sr*D_ + j + 64]);
  }
  if (t < T_) sRd[t] = rd[t*(B_*NS_) + b*NS_ + s];

  // --- weights: row t, packed (c, c+64) within each 128-half ---
  uintx16 wl0, wl1, wl2, wl3, wh0, wh1, wh2, wh3;
  {
    const float* wr = prefW + t*256;
#define LOADV(VEC, BASE) { \
    _Pragma("unroll") \
    for (int k = 0; k < 4; ++k){ \
      float4 f0 = *(const float4*)(wr + (BASE) + 4*k); \
      float4 f1 = *(const float4*)(wr + (BASE) + 64 + 4*k); \
      VEC[4*k+0] = packh(f0.x, f1.x); VEC[4*k+1] = packh(f0.y, f1.y); \
      VEC[4*k+2] = packh(f0.z, f1.z); VEC[4*k+3] = packh(f0.w, f1.w); \
    } }
    LOADV(wl0,   0) LOADV(wl1,  16) LOADV(wl2,  32) LOADV(wl3,  48)
    LOADV(wh0, 128) LOADV(wh1, 144) LOADV(wh2, 160) LOADV(wh3, 176)
#undef LOADV
  }
  const float biast = prefB[t];
  float prev1 = 0.f;   // W[:, :128].zold contribution (zold = 0 at step 0)

  // z carry in registers: (z[lane], z[lane+64]) per thread, all waves
  float v0 = latent[zi[b]*D_ + lane];
  float v1 = latent[zi[b]*D_ + lane + 64];

  __syncthreads();     // mlds/sRd staged

  for (int st = 0; st < T_; ++st){
    // --- std (ddof=1), register-only wave reduce (redundant per wave) ---
    float sm = v0 + v1, sq = v0*v0 + v1*v1;
    #pragma unroll
    for (int m = 1; m < 64; m <<= 1){
      sm += __shfl_xor(sm, m, 64);
      sq += __shfl_xor(sq, m, 64);
    }
    const float mean = sm * (1.f/128.f);
    const float var  = (sq - 128.f*mean*mean) * (1.f/127.f);
    const float sc   = 0.113f / (1e-5f + sqrtf(var));
    const float z0 = v0 * sc, z1 = v1 * sc;      // znorm at (lane, lane+64)
    if (wv == 0) xpk[lane] = packh(z0, z1);
    __syncthreads();                                   // (A)

    // --- matvec: pref[t] = prev1 + W[t,128:].znorm + b[t] ---
    float a1a = 0.f, a1b = 0.f, a2a = 0.f, a2b = 0.f;
    const uint4* xp4 = (const uint4*)xpk;
#define MACQ(WL, WH, I, E) { uint4 xq = xp4[I]; \
    mach2(xq.x, WL[(E)+0], WH[(E)+0], a1a, a2a); \
    mach2(xq.y, WL[(E)+1], WH[(E)+1], a1b, a2b); \
    mach2(xq.z, WL[(E)+2], WH[(E)+2], a1a, a2a); \
    mach2(xq.w, WL[(E)+3], WH[(E)+3], a1b, a2b); }
#define MACB(WL, WH, IB) MACQ(WL,WH,(IB)+0,0) MACQ(WL,WH,(IB)+1,4) \
                         MACQ(WL,WH,(IB)+2,8) MACQ(WL,WH,(IB)+3,12)
    MACB(wl0, wh0, 0) MACB(wl1, wh1, 4) MACB(wl2, wh2, 8) MACB(wl3, wh3, 12)
#undef MACB
#undef MACQ
    const float pref = prev1 + (a2a + a2b) + biast;
    prev1 = a1a + a1b;

    // --- softmax-cumsum-sample ---
    float e = __expf(pref);
    float cs = e;
    #pragma unroll
    for (int d = 1; d < 64; d <<= 1){
      float v = __shfl_up(cs, (unsigned)d, 64);
      if (lane >= d) cs += v;
    }
    if (lane == 63) sTot[wv] = cs;
    __syncthreads();                                   // (B)
    float off = 0.f, total = 0.f;
    #pragma unroll
    for (int i = 0; i < 8; ++i){
      float x = sTot[i];
      if (i < wv) off += x;
      total += x;
    }
    const float target = sRd[st] * total;
    const int cond = (target < off + cs) ? 1 : 0;
    int cprev = __shfl_up(cond, 1, 64);
    if (lane == 0) cprev = (target < off) ? 1 : 0;
    if (cond && !cprev) *sWhich = t;   // exactly one winner (cum monotone, exact)
    __syncthreads();                                   // (C)
    const int which = *sWhich;
    const half2v mv = u2h2(mlds[which*64 + lane]);
    v0 = z0 + (float)mv[0];
    v1 = z1 + (float)mv[1];
    if (t == 0) whichOut[c*T_ + st] = which;
  }
}

// ---------------------------------------------------------------------------
// Phase C+D fused: out[b,t] += (move[w].vw[y] + vb[y] - log(partial[w])) / NS
// ---------------------------------------------------------------------------
__global__ __launch_bounds__(256) void dots_kernel(
    const int* __restrict__ whichIn, const int* __restrict__ y,
    const float* __restrict__ move, const float* __restrict__ vw,
    const float* __restrict__ vb, const float* __restrict__ partial,
    float* __restrict__ out)
{
  const int c = blockIdx.x, b = c / NS_;
  const int wv = threadIdx.x >> 6, lane = threadIdx.x & 63;
  for (int st = wv; st < T_; st += 4){
    const int w  = whichIn[c*T_ + st];
    const int yr = y[b*T_ + st];
    const float* mp = move + w*D_;
    const float* vp = vw + yr*D_;
    float p = mp[lane]*vp[lane] + mp[lane+64]*vp[lane+64];
    #pragma unroll
    for (int m = 1; m < 64; m <<= 1) p += __shfl_xor(p, m, 64);
    if (lane == 0)
      atomicAdd(&out[b*T_ + st], (p + vb[yr] - logf(partial[w])) * (1.f/NS_));
  }
}

extern "C" void kernel_launch(void* const* d_in, const int* in_sizes, int n_in,
                              void* d_out, int out_size, void* d_ws, size_t ws_size,
                              hipStream_t stream)
{
  const int*   zi     = (const int*)d_in[0];
  const int*   y      = (const int*)d_in[1];
  const float* rd     = (const float*)d_in[2];
  const float* latent = (const float*)d_in[3];
  const float* prefW  = (const float*)d_in[4];
  const float* prefB  = (const float*)d_in[5];
  const float* move   = (const float*)d_in[6];
  const float* vw     = (const float*)d_in[7];
  const float* vb     = (const float*)d_in[8];
  float* out = (float*)d_out;

  float* partial = (float*)d_ws;                       // 512 f32
  int*   which   = (int*)((char*)d_ws + 2048);         // 160*32 i32

  static const int scan_lds = 512 + ST_*64*4;          // 131584 B
  hipFuncSetAttribute((const void*)scan_kernel,
                      hipFuncAttributeMaxDynamicSharedMemorySize, scan_lds);

  hipMemsetAsync(partial, 0, ST_*sizeof(float), stream);
  hipMemsetAsync(out, 0, B_*T_*sizeof(float), stream);
  hipLaunchKernelGGL(logz_kernel, dim3(125, 8), dim3(256), 0, stream,
                     move, vw, vb, partial);
  hipLaunchKernelGGL(scan_kernel, dim3(NCHAIN), dim3(512), scan_lds, stream,
                     zi, latent, prefW, prefB, move, rd, which);
  hipLaunchKernelGGL(dots_kernel, dim3(NCHAIN), dim3(256), 0, stream,
                     which, y, move, vw, vb, partial, out);
}

// Round 5
// 110.740 us; speedup vs baseline: 1.1649x; 1.1649x over previous
//
#include <hip/hip_runtime.h>
#include <hip/hip_bf16.h>

#define B_ 16
#define T_ 32
#define NS_ 10
#define D_ 128
#define ST_ 512
#define V_ 32000
#define NCHAIN 160

using short8  = __attribute__((ext_vector_type(8))) short;
using f32x4   = __attribute__((ext_vector_type(4))) float;
using half8   = __attribute__((ext_vector_type(8))) _Float16;
using half2v  = __attribute__((ext_vector_type(2))) _Float16;

__device__ __forceinline__ unsigned short f2bf(float f){
  unsigned u = __float_as_uint(f);
  u += 0x7FFFu + ((u >> 16) & 1u);          // RNE to bf16
  return (unsigned short)(u >> 16);
}
__device__ __forceinline__ unsigned short f2h(float f){
  return __builtin_bit_cast(unsigned short, (_Float16)f);
}
__device__ __forceinline__ float h2f(unsigned u, int hi){  // hi in {0,1}, const after unroll
  half2v h = __builtin_bit_cast(half2v, u);
  return (float)h[hi];
}
__device__ __forceinline__ float readlane_f(float v, int lane){
  return __int_as_float(__builtin_amdgcn_readlane(__float_as_int(v), lane));
}

// wave64 inclusive scan via DPP (rocPRIM pattern): 6 ops, VALU latency
#define DPPADD(x, ctrl, rm) { \
  int _t = __builtin_amdgcn_update_dpp(0, __float_as_int(x), ctrl, rm, 0xf, true); \
  x += __int_as_float(_t); }

// ---------------------------------------------------------------------------
// tables_kernel: C[w][ct] = move_w . Brow(ct), ct in [0,1536):
//   ct<512: Brow = W[ct][128:]  -> Hh ;  ct<1024: W[ct-512][:128] -> Lh ;
//   else:   move[ct-1024]       -> Gh.   f16 MFMA, f16 outputs.
// grid (6,8): 256 cols x 64 w-rows per block.
// ---------------------------------------------------------------------------
__global__ __launch_bounds__(256) void tables_kernel(
    const float* __restrict__ prefW, const float* __restrict__ move,
    unsigned short* __restrict__ Hh, unsigned short* __restrict__ Lh,
    unsigned short* __restrict__ Gh)
{
  const int sg = blockIdx.y, vc = blockIdx.x;
  const int wv = threadIdx.x >> 6, lane = threadIdx.x & 63;
  const int c16 = lane & 15, q = lane >> 4;

  half8 afr[4][4];
  #pragma unroll
  for (int rt = 0; rt < 4; ++rt){
    const float* mp = move + (sg*64 + rt*16 + c16)*D_ + q*8;
    #pragma unroll
    for (int kk = 0; kk < 4; ++kk){
      float4 f0 = *(const float4*)(mp + kk*32);
      float4 f1 = *(const float4*)(mp + kk*32 + 4);
      half8 a;
      a[0]=(_Float16)f0.x; a[1]=(_Float16)f0.y; a[2]=(_Float16)f0.z; a[3]=(_Float16)f0.w;
      a[4]=(_Float16)f1.x; a[5]=(_Float16)f1.y; a[6]=(_Float16)f1.z; a[7]=(_Float16)f1.w;
      afr[rt][kk] = a;
    }
  }
  for (int it = 0; it < 4; ++it){
    const int ct = vc*256 + it*64 + wv*16 + c16;   // 0..1535, 16-tiles never straddle 512-bounds
    const float* bp; unsigned short* base; int ccol;
    if (ct < 512)      { bp = prefW + ct*256 + 128;      base = Hh; ccol = ct; }
    else if (ct < 1024){ bp = prefW + (ct-512)*256;      base = Lh; ccol = ct-512; }
    else               { bp = move + (ct-1024)*128;      base = Gh; ccol = ct-1024; }
    half8 bfr[4];
    #pragma unroll
    for (int kk = 0; kk < 4; ++kk){
      float4 f0 = *(const float4*)(bp + q*8 + kk*32);
      float4 f1 = *(const float4*)(bp + q*8 + kk*32 + 4);
      half8 bb;
      bb[0]=(_Float16)f0.x; bb[1]=(_Float16)f0.y; bb[2]=(_Float16)f0.z; bb[3]=(_Float16)f0.w;
      bb[4]=(_Float16)f1.x; bb[5]=(_Float16)f1.y; bb[6]=(_Float16)f1.z; bb[7]=(_Float16)f1.w;
      bfr[kk] = bb;
    }
    #pragma unroll
    for (int rt = 0; rt < 4; ++rt){
      f32x4 acc = {0.f,0.f,0.f,0.f};
      #pragma unroll
      for (int kk = 0; kk < 4; ++kk)
        acc = __builtin_amdgcn_mfma_f32_16x16x32_f16(afr[rt][kk], bfr[kk], acc, 0, 0, 0);
      #pragma unroll
      for (int r = 0; r < 4; ++r){
        const int w = sg*64 + rt*16 + q*4 + r;
        base[w*ST_ + ccol] = f2h(acc[r]);
      }
    }
  }
}

// ---------------------------------------------------------------------------
// init_kernel: per-batch z0 projections + per-move sums + zeroing.
// grid 16 (b), 512 threads (t).
// ---------------------------------------------------------------------------
__global__ __launch_bounds__(512) void init_kernel(
    const int* __restrict__ zi, const float* __restrict__ latent,
    const float* __restrict__ prefW, const float* __restrict__ move,
    float* __restrict__ HU0, float* __restrict__ LU0, float* __restrict__ D0,
    float2* __restrict__ S0, float2* __restrict__ SM,
    float* __restrict__ partial, float* __restrict__ out)
{
  const int b = blockIdx.x, t = threadIdx.x;
  __shared__ float zl[128];
  if (t < 128) zl[t] = latent[zi[b]*D_ + t];
  __syncthreads();

  const float* wr = prefW + t*256;
  const float* mv = move + t*128;
  float hu = 0.f, lu = 0.f, d0 = 0.f;
  #pragma unroll 8
  for (int j = 0; j < 128; j += 4){
    float4 w0 = *(const float4*)(wr + j);
    float4 w1 = *(const float4*)(wr + 128 + j);
    float4 m  = *(const float4*)(mv + j);
    float4 z  = *(const float4*)(&zl[j]);
    lu += w0.x*z.x + w0.y*z.y + w0.z*z.z + w0.w*z.w;
    hu += w1.x*z.x + w1.y*z.y + w1.z*z.z + w1.w*z.w;
    d0 += m.x*z.x + m.y*z.y + m.z*z.z + m.w*z.w;
  }
  HU0[b*ST_ + t] = hu; LU0[b*ST_ + t] = lu; D0[b*ST_ + t] = d0;

  if (t < 64){
    float a = zl[t], bb = zl[t + 64];
    float s1 = a + bb, s2 = a*a + bb*bb;
    #pragma unroll
    for (int m = 1; m < 64; m <<= 1){ s1 += __shfl_xor(s1, m, 64); s2 += __shfl_xor(s2, m, 64); }
    if (t == 0) S0[b] = make_float2(s1, s2);
  }
  { // SM: block b covers w in [b*32, b*32+32); 16 threads per w
    const int w = b*32 + (t >> 4);
    const float* mw = move + w*128 + (t & 15)*8;
    float s1 = 0.f, s2 = 0.f;
    #pragma unroll
    for (int j = 0; j < 8; ++j){ float v = mw[j]; s1 += v; s2 += v*v; }
    #pragma unroll
    for (int m = 1; m < 16; m <<= 1){ s1 += __shfl_xor(s1, m, 64); s2 += __shfl_xor(s2, m, 64); }
    if ((t & 15) == 0) SM[w] = make_float2(s1, s2);
  }
  if (t < 32){ partial[b*32 + t] = 0.f; out[b*32 + t] = 0.f; }
}

// ---------------------------------------------------------------------------
// Phase B: partial[s] = sum_v exp(move_s . vocabW_v + vb_v)  (unchanged)
// ---------------------------------------------------------------------------
__global__ __launch_bounds__(256) void logz_kernel(
    const float* __restrict__ move, const float* __restrict__ vw,
    const float* __restrict__ vb, float* __restrict__ partial)
{
  const int sg = blockIdx.y;
  const int vc = blockIdx.x;
  const int wv = threadIdx.x >> 6;
  const int lane = threadIdx.x & 63;
  const int c16 = lane & 15, q = lane >> 4;

  __shared__ float les[64];
  if (threadIdx.x < 64) les[threadIdx.x] = 0.f;

  short8 afr[4][4];
  #pragma unroll
  for (int rt = 0; rt < 4; ++rt){
    const float* mp = move + (sg*64 + rt*16 + c16)*D_ + q*8;
    #pragma unroll
    for (int kk = 0; kk < 4; ++kk){
      float4 f0 = *(const float4*)(mp + kk*32);
      float4 f1 = *(const float4*)(mp + kk*32 + 4);
      short8 a;
      a[0]=(short)f2bf(f0.x); a[1]=(short)f2bf(f0.y);
      a[2]=(short)f2bf(f0.z); a[3]=(short)f2bf(f0.w);
      a[4]=(short)f2bf(f1.x); a[5]=(short)f2bf(f1.y);
      a[6]=(short)f2bf(f1.z); a[7]=(short)f2bf(f1.w);
      afr[rt][kk] = a;
    }
  }
  __syncthreads();

  float es[4][4] = {{0.f,0.f,0.f,0.f},{0.f,0.f,0.f,0.f},
                    {0.f,0.f,0.f,0.f},{0.f,0.f,0.f,0.f}};

  for (int it = 0; it < 4; ++it){
    const int v  = vc*256 + it*64 + wv*16 + c16;
    const float* wp = vw + v*D_ + q*8;
    short8 bfr[4];
    #pragma unroll
    for (int kk = 0; kk < 4; ++kk){
      float4 f0 = *(const float4*)(wp + kk*32);
      float4 f1 = *(const float4*)(wp + kk*32 + 4);
      short8 bb;
      bb[0]=(short)f2bf(f0.x); bb[1]=(short)f2bf(f0.y);
      bb[2]=(short)f2bf(f0.z); bb[3]=(short)f2bf(f0.w);
      bb[4]=(short)f2bf(f1.x); bb[5]=(short)f2bf(f1.y);
      bb[6]=(short)f2bf(f1.z); bb[7]=(short)f2bf(f1.w);
      bfr[kk] = bb;
    }
    const float bias = vb[v];
    #pragma unroll
    for (int rt = 0; rt < 4; ++rt){
      f32x4 acc = {0.f, 0.f, 0.f, 0.f};
      #pragma unroll
      for (int kk = 0; kk < 4; ++kk)
        acc = __builtin_amdgcn_mfma_f32_16x16x32_bf16(afr[rt][kk], bfr[kk], acc, 0, 0, 0);
      #pragma unroll
      for (int r = 0; r < 4; ++r)
        es[rt][r] += __expf(acc[r] + bias);
    }
  }
  #pragma unroll
  for (int m = 1; m < 16; m <<= 1){
    #pragma unroll
    for (int rt = 0; rt < 4; ++rt)
      #pragma unroll
      for (int r = 0; r < 4; ++r)
        es[rt][r] += __shfl_xor(es[rt][r], m, 64);
  }
  if (c16 == 0){
    #pragma unroll
    for (int rt = 0; rt < 4; ++rt)
      #pragma unroll
      for (int r = 0; r < 4; ++r)
        atomicAdd(&les[rt*16 + q*4 + r], es[rt][r]);
  }
  __syncthreads();
  if (threadIdx.x < 64) atomicAdd(&partial[sg*64 + threadIdx.x], les[threadIdx.x]);
}

// ---------------------------------------------------------------------------
// Phase A: 32-step scan as SCALAR RECURRENCES. One WAVE per chain, no LDS,
// no barriers. Lane l owns states t = 8l..8l+7.
//   pref[t] = prev1[t] + sc*HU[t] + b[t];  HU' = sc*HU + Hh[w][t];
//   prev1' = sc*LU;  LU' = prev1' + Lh[w][t];  D' = sc*D + Gh[w][t];
//   S1' = sc*S1 + SM[w].x;  S2' = sc^2*S2 + 2*sc*D[w] + SM[w].y
// ---------------------------------------------------------------------------
__global__ __launch_bounds__(64) void scan_kernel(
    const unsigned short* __restrict__ Hh, const unsigned short* __restrict__ Lh,
    const unsigned short* __restrict__ Gh, const float2* __restrict__ SM,
    const float* __restrict__ HU0, const float* __restrict__ LU0,
    const float* __restrict__ D0, const float2* __restrict__ S0,
    const float* __restrict__ prefB, const float* __restrict__ rd,
    int* __restrict__ whichOut)
{
  const int c = blockIdx.x, b = c / NS_;
  const int l = threadIdx.x;            // 64
  const int t0 = l*8;

  float HU[8], LU[8], D[8], prev1[8], bias[8];
  #pragma unroll
  for (int k = 0; k < 8; k += 4){
    float4 h = *(const float4*)(HU0 + b*ST_ + t0 + k);
    float4 u = *(const float4*)(LU0 + b*ST_ + t0 + k);
    float4 d = *(const float4*)(D0  + b*ST_ + t0 + k);
    float4 bb= *(const float4*)(prefB + t0 + k);
    HU[k]=h.x; HU[k+1]=h.y; HU[k+2]=h.z; HU[k+3]=h.w;
    LU[k]=u.x; LU[k+1]=u.y; LU[k+2]=u.z; LU[k+3]=u.w;
    D[k]=d.x;  D[k+1]=d.y;  D[k+2]=d.z;  D[k+3]=d.w;
    bias[k]=bb.x; bias[k+1]=bb.y; bias[k+2]=bb.z; bias[k+3]=bb.w;
  }
  #pragma unroll
  for (int k = 0; k < 8; ++k) prev1[k] = 0.f;
  float2 s0 = S0[b];
  float S1 = s0.x, S2 = s0.y;
  float rdreg = (l < T_) ? rd[l*(B_*NS_) + c] : 0.f;   // rd[st][b][s], c=b*10+s

  for (int st = 0; st < T_; ++st){
    const float mean = S1 * (1.f/128.f);
    const float var  = (S2 - 128.f*mean*mean) * (1.f/127.f);
    const float sc   = 0.113f / (1e-5f + sqrtf(var));

    float cum[8]; float run = 0.f;
    #pragma unroll
    for (int k = 0; k < 8; ++k){
      float pref = fmaf(sc, HU[k], prev1[k] + bias[k]);
      run += __expf(pref);
      cum[k] = run;
    }
    // wave64 inclusive scan (DPP)
    float incl = run;
    DPPADD(incl, 0x111, 0xf)   // row_shr:1
    DPPADD(incl, 0x112, 0xf)   // row_shr:2
    DPPADD(incl, 0x114, 0xf)   // row_shr:4
    DPPADD(incl, 0x118, 0xf)   // row_shr:8
    DPPADD(incl, 0x142, 0xa)   // row_bcast:15 -> rows 1,3
    DPPADD(incl, 0x143, 0xc)   // row_bcast:31 -> rows 2,3
    const float total  = readlane_f(incl, 63);
    const float target = readlane_f(rdreg, st) * total;

    const bool cond = target < incl;
    const unsigned long long bal = __ballot(cond);
    const float excl = incl - run;
    int kw = 7; float dcand = D[7];
    #pragma unroll
    for (int k = 6; k >= 0; --k){
      bool ck = target < excl + cum[k];
      kw = ck ? k : kw;
      dcand = ck ? D[k] : dcand;
    }
    int which; float dW;
    if (bal){
      const int wlane = __ffsll(bal) - 1;
      which = __builtin_amdgcn_readlane(t0 + kw, wlane);
      dW    = readlane_f(dcand, wlane);
    } else {                       // argmax-of-all-false = 0 (rare fp edge)
      which = 0;
      dW    = readlane_f(D[0], 0);
    }
    if (l == 0) whichOut[c*T_ + st] = which;

    const int rb = which*ST_ + t0;
    const uint4 hq = *(const uint4*)(Hh + rb);
    const uint4 lq = *(const uint4*)(Lh + rb);
    const uint4 gq = *(const uint4*)(Gh + rb);
    const float2 sm = SM[which];
    const unsigned ha[4] = {hq.x, hq.y, hq.z, hq.w};
    const unsigned la[4] = {lq.x, lq.y, lq.z, lq.w};
    const unsigned ga[4] = {gq.x, gq.y, gq.z, gq.w};
    #pragma unroll
    for (int k = 0; k < 8; ++k){
      const float Hk = h2f(ha[k>>1], k&1);
      const float Lk = h2f(la[k>>1], k&1);
      const float Gk = h2f(ga[k>>1], k&1);
      const float p1 = sc * LU[k];
      HU[k] = fmaf(sc, HU[k], Hk);
      LU[k] = p1 + Lk;
      D[k]  = fmaf(sc, D[k], Gk);
      prev1[k] = p1;
    }
    S1 = fmaf(sc, S1, sm.x);
    S2 = fmaf(sc*sc, S2, fmaf(2.f*sc, dW, sm.y));
  }
}

// ---------------------------------------------------------------------------
// Phase C+D fused: out[b,t] += (move[w].vw[y] + vb[y] - log(partial[w])) / NS
// ---------------------------------------------------------------------------
__global__ __launch_bounds__(256) void dots_kernel(
    const int* __restrict__ whichIn, const int* __restrict__ y,
    const float* __restrict__ move, const float* __restrict__ vw,
    const float* __restrict__ vb, const float* __restrict__ partial,
    float* __restrict__ out)
{
  const int c = blockIdx.x, b = c / NS_;
  const int wv = threadIdx.x >> 6, lane = threadIdx.x & 63;
  for (int st = wv; st < T_; st += 4){
    const int w  = whichIn[c*T_ + st];
    const int yr = y[b*T_ + st];
    const float* mp = move + w*D_;
    const float* vp = vw + yr*D_;
    float p = mp[lane]*vp[lane] + mp[lane+64]*vp[lane+64];
    #pragma unroll
    for (int m = 1; m < 64; m <<= 1) p += __shfl_xor(p, m, 64);
    if (lane == 0)
      atomicAdd(&out[b*T_ + st], (p + vb[yr] - logf(partial[w])) * (1.f/NS_));
  }
}

extern "C" void kernel_launch(void* const* d_in, const int* in_sizes, int n_in,
                              void* d_out, int out_size, void* d_ws, size_t ws_size,
                              hipStream_t stream)
{
  const int*   zi     = (const int*)d_in[0];
  const int*   y      = (const int*)d_in[1];
  const float* rd     = (const float*)d_in[2];
  const float* latent = (const float*)d_in[3];
  const float* prefW  = (const float*)d_in[4];
  const float* prefB  = (const float*)d_in[5];
  const float* move   = (const float*)d_in[6];
  const float* vw     = (const float*)d_in[7];
  const float* vb     = (const float*)d_in[8];
  float* out = (float*)d_out;

  char* ws = (char*)d_ws;                               // ~1.70 MB total
  unsigned short* Hh = (unsigned short*)(ws);           // 512 KB
  unsigned short* Lh = (unsigned short*)(ws + 524288);  // 512 KB
  unsigned short* Gh = (unsigned short*)(ws + 1048576); // 512 KB
  float2* SM    = (float2*)(ws + 1572864);              // 4 KB
  float*  HU0   = (float*)(ws + 1576960);               // 32 KB
  float*  LU0   = (float*)(ws + 1609728);               // 32 KB
  float*  D0    = (float*)(ws + 1642496);               // 32 KB
  float2* S0    = (float2*)(ws + 1675264);              // 128 B
  float*  partial = (float*)(ws + 1675392);             // 2 KB
  int*    which = (int*)(ws + 1677440);                 // 20 KB

  hipLaunchKernelGGL(tables_kernel, dim3(6, 8), dim3(256), 0, stream,
                     prefW, move, Hh, Lh, Gh);
  hipLaunchKernelGGL(init_kernel, dim3(B_), dim3(512), 0, stream,
                     zi, latent, prefW, move, HU0, LU0, D0, S0, SM, partial, out);
  hipLaunchKernelGGL(logz_kernel, dim3(125, 8), dim3(256), 0, stream,
                     move, vw, vb, partial);
  hipLaunchKernelGGL(scan_kernel, dim3(NCHAIN), dim3(64), 0, stream,
                     Hh, Lh, Gh, SM, HU0, LU0, D0, S0, prefB, rd, which);
  hipLaunchKernelGGL(dots_kernel, dim3(NCHAIN), dim3(256), 0, stream,
                     which, y, move, vw, vb, partial, out);
}

// Round 6
// 82.482 us; speedup vs baseline: 1.5640x; 1.3426x over previous
//
#include <hip/hip_runtime.h>
#include <hip/hip_bf16.h>

#define B_ 16
#define T_ 32
#define NS_ 10
#define D_ 128
#define ST_ 512
#define V_ 32000
#define NCHAIN 160

using short8  = __attribute__((ext_vector_type(8))) short;
using f32x4   = __attribute__((ext_vector_type(4))) float;
using half8   = __attribute__((ext_vector_type(8))) _Float16;
using half2v  = __attribute__((ext_vector_type(2))) _Float16;

__device__ __forceinline__ unsigned short f2bf(float f){
  unsigned u = __float_as_uint(f);
  u += 0x7FFFu + ((u >> 16) & 1u);          // RNE to bf16
  return (unsigned short)(u >> 16);
}
__device__ __forceinline__ unsigned packbf(float a, float b){
  return ((unsigned)f2bf(b) << 16) | (unsigned)f2bf(a);
}
__device__ __forceinline__ unsigned short f2h(float f){
  return __builtin_bit_cast(unsigned short, (_Float16)f);
}
__device__ __forceinline__ float h2f(unsigned u, int hi){
  half2v h = __builtin_bit_cast(half2v, u);
  return (float)h[hi];
}
__device__ __forceinline__ float readlane_f(float v, int lane){
  return __int_as_float(__builtin_amdgcn_readlane(__float_as_int(v), lane));
}

// wave64 inclusive scan via DPP: 6 ops
#define DPPADD(x, ctrl, rm) { \
  int _t = __builtin_amdgcn_update_dpp(0, __float_as_int(x), ctrl, rm, 0xf, true); \
  x += __int_as_float(_t); }

// ---------------------------------------------------------------------------
// prep_kernel: 64 blocks x 256 thr.
//  blocks 0..47  : tables  C[w][ct] = move_w . Brow(ct) (f16 MFMA -> Hh/Lh/Gh)
//  blocks 48..63 : per-batch z0 projections, S0, SM, mbf (bf16 move), zeroing
// ---------------------------------------------------------------------------
__global__ __launch_bounds__(256) void prep_kernel(
    const int* __restrict__ zi, const float* __restrict__ latent,
    const float* __restrict__ prefW, const float* __restrict__ move,
    unsigned short* __restrict__ Hh, unsigned short* __restrict__ Lh,
    unsigned short* __restrict__ Gh,
    float* __restrict__ HU0, float* __restrict__ LU0, float* __restrict__ D0,
    float2* __restrict__ S0, float2* __restrict__ SM,
    unsigned* __restrict__ mbf, float* __restrict__ partial,
    float* __restrict__ out)
{
  if (blockIdx.x < 48){
    const int sg = blockIdx.x / 6, vc = blockIdx.x % 6;
    const int wv = threadIdx.x >> 6, lane = threadIdx.x & 63;
    const int c16 = lane & 15, q = lane >> 4;

    half8 afr[4][4];
    #pragma unroll
    for (int rt = 0; rt < 4; ++rt){
      const float* mp = move + (sg*64 + rt*16 + c16)*D_ + q*8;
      #pragma unroll
      for (int kk = 0; kk < 4; ++kk){
        float4 f0 = *(const float4*)(mp + kk*32);
        float4 f1 = *(const float4*)(mp + kk*32 + 4);
        half8 a;
        a[0]=(_Float16)f0.x; a[1]=(_Float16)f0.y; a[2]=(_Float16)f0.z; a[3]=(_Float16)f0.w;
        a[4]=(_Float16)f1.x; a[5]=(_Float16)f1.y; a[6]=(_Float16)f1.z; a[7]=(_Float16)f1.w;
        afr[rt][kk] = a;
      }
    }
    for (int it = 0; it < 4; ++it){
      const int ct = vc*256 + it*64 + wv*16 + c16;   // tiles never straddle 512-bounds
      const float* bp; unsigned short* base; int ccol;
      if (ct < 512)      { bp = prefW + ct*256 + 128; base = Hh; ccol = ct; }
      else if (ct < 1024){ bp = prefW + (ct-512)*256; base = Lh; ccol = ct-512; }
      else               { bp = move + (ct-1024)*128; base = Gh; ccol = ct-1024; }
      half8 bfr[4];
      #pragma unroll
      for (int kk = 0; kk < 4; ++kk){
        float4 f0 = *(const float4*)(bp + q*8 + kk*32);
        float4 f1 = *(const float4*)(bp + q*8 + kk*32 + 4);
        half8 bb;
        bb[0]=(_Float16)f0.x; bb[1]=(_Float16)f0.y; bb[2]=(_Float16)f0.z; bb[3]=(_Float16)f0.w;
        bb[4]=(_Float16)f1.x; bb[5]=(_Float16)f1.y; bb[6]=(_Float16)f1.z; bb[7]=(_Float16)f1.w;
        bfr[kk] = bb;
      }
      #pragma unroll
      for (int rt = 0; rt < 4; ++rt){
        f32x4 acc = {0.f,0.f,0.f,0.f};
        #pragma unroll
        for (int kk = 0; kk < 4; ++kk)
          acc = __builtin_amdgcn_mfma_f32_16x16x32_f16(afr[rt][kk], bfr[kk], acc, 0, 0, 0);
        #pragma unroll
        for (int r = 0; r < 4; ++r){
          const int w = sg*64 + rt*16 + q*4 + r;
          base[w*ST_ + ccol] = f2h(acc[r]);
        }
      }
    }
  } else {
    const int b = blockIdx.x - 48, t = threadIdx.x;
    __shared__ float zl[128];
    if (t < 128) zl[t] = latent[zi[b]*D_ + t];
    __syncthreads();

    #pragma unroll
    for (int ii = 0; ii < 2; ++ii){
      const int sidx = t + ii*256;
      const float* wr = prefW + sidx*256;
      const float* mv = move + sidx*128;
      float hu = 0.f, lu = 0.f, d0 = 0.f;
      #pragma unroll 8
      for (int j = 0; j < 128; j += 4){
        float4 w0 = *(const float4*)(wr + j);
        float4 w1 = *(const float4*)(wr + 128 + j);
        float4 m  = *(const float4*)(mv + j);
        float4 z  = *(const float4*)(&zl[j]);
        lu += w0.x*z.x + w0.y*z.y + w0.z*z.z + w0.w*z.w;
        hu += w1.x*z.x + w1.y*z.y + w1.z*z.z + w1.w*z.w;
        d0 += m.x*z.x + m.y*z.y + m.z*z.z + m.w*z.w;
      }
      HU0[b*ST_ + sidx] = hu; LU0[b*ST_ + sidx] = lu; D0[b*ST_ + sidx] = d0;
    }
    if (t < 64){
      float a = zl[t], bb = zl[t + 64];
      float s1 = a + bb, s2 = a*a + bb*bb;
      #pragma unroll
      for (int m = 1; m < 64; m <<= 1){ s1 += __shfl_xor(s1, m, 64); s2 += __shfl_xor(s2, m, 64); }
      if (t == 0) S0[b] = make_float2(s1, s2);
    }
    { // SM + mbf: row = b*32 + (t>>3), 8 threads/row, 16 cols each
      const int w = b*32 + (t >> 3);
      const float* mw = move + w*128 + (t & 7)*16;
      float4 m0 = *(const float4*)(mw),   m1 = *(const float4*)(mw+4);
      float4 m2 = *(const float4*)(mw+8), m3 = *(const float4*)(mw+12);
      float s1 = m0.x+m0.y+m0.z+m0.w + m1.x+m1.y+m1.z+m1.w
               + m2.x+m2.y+m2.z+m2.w + m3.x+m3.y+m3.z+m3.w;
      float s2 = m0.x*m0.x+m0.y*m0.y+m0.z*m0.z+m0.w*m0.w
               + m1.x*m1.x+m1.y*m1.y+m1.z*m1.z+m1.w*m1.w
               + m2.x*m2.x+m2.y*m2.y+m2.z*m2.z+m2.w*m2.w
               + m3.x*m3.x+m3.y*m3.y+m3.z*m3.z+m3.w*m3.w;
      #pragma unroll
      for (int m = 1; m < 8; m <<= 1){ s1 += __shfl_xor(s1, m, 64); s2 += __shfl_xor(s2, m, 64); }
      if ((t & 7) == 0) SM[w] = make_float2(s1, s2);
      unsigned* dst = mbf + w*64 + (t & 7)*8;
      dst[0] = packbf(m0.x,m0.y); dst[1] = packbf(m0.z,m0.w);
      dst[2] = packbf(m1.x,m1.y); dst[3] = packbf(m1.z,m1.w);
      dst[4] = packbf(m2.x,m2.y); dst[5] = packbf(m2.z,m2.w);
      dst[6] = packbf(m3.x,m3.y); dst[7] = packbf(m3.z,m3.w);
    }
    if (t < 32){ partial[b*32 + t] = 0.f; out[b*32 + t] = 0.f; }
  }
}

// ---------------------------------------------------------------------------
// logz_kernel (rewritten): vw read ONCE. 250 blocks x 256 thr; each wave owns
// 32 vocab rows (A, registers); B = move bf16 staged in LDS (XOR-swizzled).
// D[vocab][state]; exp-sum into esl[32] regs; wave shfl-reduce; LDS block
// reduce; 512 global atomics/block.
// ---------------------------------------------------------------------------
__global__ __launch_bounds__(256) void logz_kernel(
    const unsigned* __restrict__ mbf, const float* __restrict__ vw,
    const float* __restrict__ vb, float* __restrict__ partial)
{
  extern __shared__ __align__(16) char lsm[];         // 131072 move + 8192 les
  float* les = (float*)(lsm + 131072);                // [4][512]
  const int t = threadIdx.x, lane = t & 63, wv = t >> 6;

  // stage mbf -> LDS with XOR swizzle (row-major bf16 [512][128])
  #pragma unroll 8
  for (int i = 0; i < 128; ++i){
    const int f = t + i*256;
    const int row = f >> 6, colu = f & 63;
    unsigned byte = row*256 + colu*4;
    byte ^= ((row & 7) << 4);
    *(unsigned*)(lsm + byte) = mbf[f];
  }
  #pragma unroll
  for (int i = 0; i < 8; ++i) les[t + i*256] = 0.f;

  // A fragments: 32 vocab rows per wave (read once from fp32 vw)
  const int vbase = blockIdx.x*128 + wv*32;
  short8 afr[2][4];
  float vbr[2][4];
  #pragma unroll
  for (int vt = 0; vt < 2; ++vt){
    const int vr = vbase + vt*16 + (lane & 15);
    const float* wp = vw + vr*D_ + (lane >> 4)*8;
    #pragma unroll
    for (int kk = 0; kk < 4; ++kk){
      float4 f0 = *(const float4*)(wp + kk*32);
      float4 f1 = *(const float4*)(wp + kk*32 + 4);
      short8 a;
      a[0]=(short)f2bf(f0.x); a[1]=(short)f2bf(f0.y);
      a[2]=(short)f2bf(f0.z); a[3]=(short)f2bf(f0.w);
      a[4]=(short)f2bf(f1.x); a[5]=(short)f2bf(f1.y);
      a[6]=(short)f2bf(f1.z); a[7]=(short)f2bf(f1.w);
      afr[vt][kk] = a;
    }
    #pragma unroll
    for (int r = 0; r < 4; ++r)
      vbr[vt][r] = vb[vbase + vt*16 + (lane >> 4)*4 + r];
  }
  __syncthreads();

  float esl[32];
  #pragma unroll
  for (int s = 0; s < 32; ++s) esl[s] = 0.f;

  #pragma unroll
  for (int s = 0; s < 32; ++s){
    short8 bfr[4];
    #pragma unroll
    for (int kk = 0; kk < 4; ++kk){
      const int row = s*16 + (lane & 15);
      unsigned byte = row*256 + ((lane >> 4)*8 + kk*32)*2;
      byte ^= ((row & 7) << 4);
      bfr[kk] = *(const short8*)(lsm + byte);
    }
    #pragma unroll
    for (int vt = 0; vt < 2; ++vt){
      f32x4 acc = {0.f,0.f,0.f,0.f};
      #pragma unroll
      for (int kk = 0; kk < 4; ++kk)
        acc = __builtin_amdgcn_mfma_f32_16x16x32_bf16(afr[vt][kk], bfr[kk], acc, 0, 0, 0);
      #pragma unroll
      for (int r = 0; r < 4; ++r)
        esl[s] += __expf(acc[r] + vbr[vt][r]);
    }
  }
  #pragma unroll
  for (int s = 0; s < 32; ++s){
    esl[s] += __shfl_xor(esl[s], 16, 64);
    esl[s] += __shfl_xor(esl[s], 32, 64);
  }
  if (lane < 16){
    #pragma unroll
    for (int s = 0; s < 32; ++s) les[wv*512 + s*16 + lane] = esl[s];
  }
  __syncthreads();
  #pragma unroll
  for (int i = 0; i < 2; ++i){
    const int st = t + i*256;
    atomicAdd(&partial[st], les[st] + les[512+st] + les[1024+st] + les[1536+st]);
  }
}

// ---------------------------------------------------------------------------
// Phase A: 32-step scan as scalar recurrences. One wave per chain. (unchanged)
// ---------------------------------------------------------------------------
__global__ __launch_bounds__(64) void scan_kernel(
    const unsigned short* __restrict__ Hh, const unsigned short* __restrict__ Lh,
    const unsigned short* __restrict__ Gh, const float2* __restrict__ SM,
    const float* __restrict__ HU0, const float* __restrict__ LU0,
    const float* __restrict__ D0, const float2* __restrict__ S0,
    const float* __restrict__ prefB, const float* __restrict__ rd,
    int* __restrict__ whichOut)
{
  const int c = blockIdx.x, b = c / NS_;
  const int l = threadIdx.x;
  const int t0 = l*8;

  float HU[8], LU[8], D[8], prev1[8], bias[8];
  #pragma unroll
  for (int k = 0; k < 8; k += 4){
    float4 h = *(const float4*)(HU0 + b*ST_ + t0 + k);
    float4 u = *(const float4*)(LU0 + b*ST_ + t0 + k);
    float4 d = *(const float4*)(D0  + b*ST_ + t0 + k);
    float4 bb= *(const float4*)(prefB + t0 + k);
    HU[k]=h.x; HU[k+1]=h.y; HU[k+2]=h.z; HU[k+3]=h.w;
    LU[k]=u.x; LU[k+1]=u.y; LU[k+2]=u.z; LU[k+3]=u.w;
    D[k]=d.x;  D[k+1]=d.y;  D[k+2]=d.z;  D[k+3]=d.w;
    bias[k]=bb.x; bias[k+1]=bb.y; bias[k+2]=bb.z; bias[k+3]=bb.w;
  }
  #pragma unroll
  for (int k = 0; k < 8; ++k) prev1[k] = 0.f;
  float2 s0 = S0[b];
  float S1 = s0.x, S2 = s0.y;
  float rdreg = (l < T_) ? rd[l*(B_*NS_) + c] : 0.f;

  for (int st = 0; st < T_; ++st){
    const float mean = S1 * (1.f/128.f);
    const float var  = (S2 - 128.f*mean*mean) * (1.f/127.f);
    const float sc   = 0.113f / (1e-5f + sqrtf(var));

    float cum[8]; float run = 0.f;
    #pragma unroll
    for (int k = 0; k < 8; ++k){
      float pref = fmaf(sc, HU[k], prev1[k] + bias[k]);
      run += __expf(pref);
      cum[k] = run;
    }
    float incl = run;
    DPPADD(incl, 0x111, 0xf)
    DPPADD(incl, 0x112, 0xf)
    DPPADD(incl, 0x114, 0xf)
    DPPADD(incl, 0x118, 0xf)
    DPPADD(incl, 0x142, 0xa)
    DPPADD(incl, 0x143, 0xc)
    const float total  = readlane_f(incl, 63);
    const float target = readlane_f(rdreg, st) * total;

    const bool cond = target < incl;
    const unsigned long long bal = __ballot(cond);
    const float excl = incl - run;
    int kw = 7; float dcand = D[7];
    #pragma unroll
    for (int k = 6; k >= 0; --k){
      bool ck = target < excl + cum[k];
      kw = ck ? k : kw;
      dcand = ck ? D[k] : dcand;
    }
    int which; float dW;
    if (bal){
      const int wlane = __ffsll(bal) - 1;
      which = __builtin_amdgcn_readlane(t0 + kw, wlane);
      dW    = readlane_f(dcand, wlane);
    } else {
      which = 0;
      dW    = readlane_f(D[0], 0);
    }
    if (l == 0) whichOut[c*T_ + st] = which;

    const int rb = which*ST_ + t0;
    const uint4 hq = *(const uint4*)(Hh + rb);
    const uint4 lq = *(const uint4*)(Lh + rb);
    const uint4 gq = *(const uint4*)(Gh + rb);
    const float2 sm = SM[which];
    const unsigned ha[4] = {hq.x, hq.y, hq.z, hq.w};
    const unsigned la[4] = {lq.x, lq.y, lq.z, lq.w};
    const unsigned ga[4] = {gq.x, gq.y, gq.z, gq.w};
    #pragma unroll
    for (int k = 0; k < 8; ++k){
      const float Hk = h2f(ha[k>>1], k&1);
      const float Lk = h2f(la[k>>1], k&1);
      const float Gk = h2f(ga[k>>1], k&1);
      const float p1 = sc * LU[k];
      HU[k] = fmaf(sc, HU[k], Hk);
      LU[k] = p1 + Lk;
      D[k]  = fmaf(sc, D[k], Gk);
      prev1[k] = p1;
    }
    S1 = fmaf(sc, S1, sm.x);
    S2 = fmaf(sc*sc, S2, fmaf(2.f*sc, dW, sm.y));
  }
}

// ---------------------------------------------------------------------------
// Phase C+D fused: out[b,t] += (move[w].vw[y] + vb[y] - log(partial[w])) / NS
// ---------------------------------------------------------------------------
__global__ __launch_bounds__(256) void dots_kernel(
    const int* __restrict__ whichIn, const int* __restrict__ y,
    const float* __restrict__ move, const float* __restrict__ vw,
    const float* __restrict__ vb, const float* __restrict__ partial,
    float* __restrict__ out)
{
  const int c = blockIdx.x, b = c / NS_;
  const int wv = threadIdx.x >> 6, lane = threadIdx.x & 63;
  for (int st = wv; st < T_; st += 4){
    const int w  = whichIn[c*T_ + st];
    const int yr = y[b*T_ + st];
    const float* mp = move + w*D_;
    const float* vp = vw + yr*D_;
    float p = mp[lane]*vp[lane] + mp[lane+64]*vp[lane+64];
    #pragma unroll
    for (int m = 1; m < 64; m <<= 1) p += __shfl_xor(p, m, 64);
    if (lane == 0)
      atomicAdd(&out[b*T_ + st], (p + vb[yr] - logf(partial[w])) * (1.f/NS_));
  }
}

extern "C" void kernel_launch(void* const* d_in, const int* in_sizes, int n_in,
                              void* d_out, int out_size, void* d_ws, size_t ws_size,
                              hipStream_t stream)
{
  const int*   zi     = (const int*)d_in[0];
  const int*   y      = (const int*)d_in[1];
  const float* rd     = (const float*)d_in[2];
  const float* latent = (const float*)d_in[3];
  const float* prefW  = (const float*)d_in[4];
  const float* prefB  = (const float*)d_in[5];
  const float* move   = (const float*)d_in[6];
  const float* vw     = (const float*)d_in[7];
  const float* vb     = (const float*)d_in[8];
  float* out = (float*)d_out;

  char* ws = (char*)d_ws;
  unsigned short* Hh = (unsigned short*)(ws);           // 512 KB
  unsigned short* Lh = (unsigned short*)(ws + 524288);  // 512 KB
  unsigned short* Gh = (unsigned short*)(ws + 1048576); // 512 KB
  float2* SM    = (float2*)(ws + 1572864);              // 4 KB
  float*  HU0   = (float*)(ws + 1576960);               // 32 KB
  float*  LU0   = (float*)(ws + 1609728);               // 32 KB
  float*  D0    = (float*)(ws + 1642496);               // 32 KB
  float2* S0    = (float2*)(ws + 1675264);              // 128 B
  float*  partial = (float*)(ws + 1675392);             // 2 KB
  int*    which = (int*)(ws + 1677440);                 // 20 KB
  unsigned* mbf = (unsigned*)(ws + 1697920);            // 128 KB (bf16 move)

  static const int logz_lds = 131072 + 8192;            // 139264 B
  hipFuncSetAttribute((const void*)logz_kernel,
                      hipFuncAttributeMaxDynamicSharedMemorySize, logz_lds);

  hipLaunchKernelGGL(prep_kernel, dim3(64), dim3(256), 0, stream,
                     zi, latent, prefW, move, Hh, Lh, Gh,
                     HU0, LU0, D0, S0, SM, mbf, partial, out);
  hipLaunchKernelGGL(logz_kernel, dim3(250), dim3(256), logz_lds, stream,
                     mbf, vw, vb, partial);
  hipLaunchKernelGGL(scan_kernel, dim3(NCHAIN), dim3(64), 0, stream,
                     Hh, Lh, Gh, SM, HU0, LU0, D0, S0, prefB, rd, which);
  hipLaunchKernelGGL(dots_kernel, dim3(NCHAIN), dim3(256), 0, stream,
                     which, y, move, vw, vb, partial, out);
}

// Round 7
// 65.126 us; speedup vs baseline: 1.9808x; 1.2665x over previous
//
#include <hip/hip_runtime.h>
#include <hip/hip_bf16.h>

#define B_ 16
#define T_ 32
#define NS_ 10
#define D_ 128
#define ST_ 512
#define V_ 32000
#define NCHAIN 160

using short8  = __attribute__((ext_vector_type(8))) short;
using f32x4   = __attribute__((ext_vector_type(4))) float;
using half8   = __attribute__((ext_vector_type(8))) _Float16;
using half2v  = __attribute__((ext_vector_type(2))) _Float16;

__device__ __forceinline__ unsigned short f2bf(float f){
  unsigned u = __float_as_uint(f);
  u += 0x7FFFu + ((u >> 16) & 1u);          // RNE to bf16
  return (unsigned short)(u >> 16);
}
__device__ __forceinline__ unsigned packbf(float a, float b){
  return ((unsigned)f2bf(b) << 16) | (unsigned)f2bf(a);
}
__device__ __forceinline__ unsigned short f2h(float f){
  return __builtin_bit_cast(unsigned short, (_Float16)f);
}
__device__ __forceinline__ float h2f(unsigned u, int hi){
  half2v h = __builtin_bit_cast(half2v, u);
  return (float)h[hi];
}
__device__ __forceinline__ float readlane_f(float v, int lane){
  return __int_as_float(__builtin_amdgcn_readlane(__float_as_int(v), lane));
}

// wave64 inclusive scan via DPP: 6 ops
#define DPPADD(x, ctrl, rm) { \
  int _t = __builtin_amdgcn_update_dpp(0, __float_as_int(x), ctrl, rm, 0xf, true); \
  x += __int_as_float(_t); }

// ---------------------------------------------------------------------------
// prep_kernel: 64 blocks x 256 thr.
//  blocks 0..47  : tables  C[w][ct] = move_w . Brow(ct) (f16 MFMA -> Hh/Lh/Gh)
//  blocks 48..63 : per-batch z0 projections, S0, SM, mbf (bf16 move), zero partial
// ---------------------------------------------------------------------------
__global__ __launch_bounds__(256) void prep_kernel(
    const int* __restrict__ zi, const float* __restrict__ latent,
    const float* __restrict__ prefW, const float* __restrict__ move,
    unsigned short* __restrict__ Hh, unsigned short* __restrict__ Lh,
    unsigned short* __restrict__ Gh,
    float* __restrict__ HU0, float* __restrict__ LU0, float* __restrict__ D0,
    float2* __restrict__ S0, float2* __restrict__ SM,
    unsigned* __restrict__ mbf, float* __restrict__ partial)
{
  if (blockIdx.x < 48){
    const int sg = blockIdx.x / 6, vc = blockIdx.x % 6;
    const int wv = threadIdx.x >> 6, lane = threadIdx.x & 63;
    const int c16 = lane & 15, q = lane >> 4;

    half8 afr[4][4];
    #pragma unroll
    for (int rt = 0; rt < 4; ++rt){
      const float* mp = move + (sg*64 + rt*16 + c16)*D_ + q*8;
      #pragma unroll
      for (int kk = 0; kk < 4; ++kk){
        float4 f0 = *(const float4*)(mp + kk*32);
        float4 f1 = *(const float4*)(mp + kk*32 + 4);
        half8 a;
        a[0]=(_Float16)f0.x; a[1]=(_Float16)f0.y; a[2]=(_Float16)f0.z; a[3]=(_Float16)f0.w;
        a[4]=(_Float16)f1.x; a[5]=(_Float16)f1.y; a[6]=(_Float16)f1.z; a[7]=(_Float16)f1.w;
        afr[rt][kk] = a;
      }
    }
    for (int it = 0; it < 4; ++it){
      const int ct = vc*256 + it*64 + wv*16 + c16;   // tiles never straddle 512-bounds
      const float* bp; unsigned short* base; int ccol;
      if (ct < 512)      { bp = prefW + ct*256 + 128; base = Hh; ccol = ct; }
      else if (ct < 1024){ bp = prefW + (ct-512)*256; base = Lh; ccol = ct-512; }
      else               { bp = move + (ct-1024)*128; base = Gh; ccol = ct-1024; }
      half8 bfr[4];
      #pragma unroll
      for (int kk = 0; kk < 4; ++kk){
        float4 f0 = *(const float4*)(bp + q*8 + kk*32);
        float4 f1 = *(const float4*)(bp + q*8 + kk*32 + 4);
        half8 bb;
        bb[0]=(_Float16)f0.x; bb[1]=(_Float16)f0.y; bb[2]=(_Float16)f0.z; bb[3]=(_Float16)f0.w;
        bb[4]=(_Float16)f1.x; bb[5]=(_Float16)f1.y; bb[6]=(_Float16)f1.z; bb[7]=(_Float16)f1.w;
        bfr[kk] = bb;
      }
      #pragma unroll
      for (int rt = 0; rt < 4; ++rt){
        f32x4 acc = {0.f,0.f,0.f,0.f};
        #pragma unroll
        for (int kk = 0; kk < 4; ++kk)
          acc = __builtin_amdgcn_mfma_f32_16x16x32_f16(afr[rt][kk], bfr[kk], acc, 0, 0, 0);
        #pragma unroll
        for (int r = 0; r < 4; ++r){
          const int w = sg*64 + rt*16 + q*4 + r;
          base[w*ST_ + ccol] = f2h(acc[r]);
        }
      }
    }
  } else {
    const int b = blockIdx.x - 48, t = threadIdx.x;
    __shared__ float zl[128];
    if (t < 128) zl[t] = latent[zi[b]*D_ + t];
    __syncthreads();

    #pragma unroll
    for (int ii = 0; ii < 2; ++ii){
      const int sidx = t + ii*256;
      const float* wr = prefW + sidx*256;
      const float* mv = move + sidx*128;
      float hu = 0.f, lu = 0.f, d0 = 0.f;
      #pragma unroll 8
      for (int j = 0; j < 128; j += 4){
        float4 w0 = *(const float4*)(wr + j);
        float4 w1 = *(const float4*)(wr + 128 + j);
        float4 m  = *(const float4*)(mv + j);
        float4 z  = *(const float4*)(&zl[j]);
        lu += w0.x*z.x + w0.y*z.y + w0.z*z.z + w0.w*z.w;
        hu += w1.x*z.x + w1.y*z.y + w1.z*z.z + w1.w*z.w;
        d0 += m.x*z.x + m.y*z.y + m.z*z.z + m.w*z.w;
      }
      HU0[b*ST_ + sidx] = hu; LU0[b*ST_ + sidx] = lu; D0[b*ST_ + sidx] = d0;
    }
    if (t < 64){
      float a = zl[t], bb = zl[t + 64];
      float s1 = a + bb, s2 = a*a + bb*bb;
      #pragma unroll
      for (int m = 1; m < 64; m <<= 1){ s1 += __shfl_xor(s1, m, 64); s2 += __shfl_xor(s2, m, 64); }
      if (t == 0) S0[b] = make_float2(s1, s2);
    }
    { // SM + mbf: row = b*32 + (t>>3), 8 threads/row, 16 cols each
      const int w = b*32 + (t >> 3);
      const float* mw = move + w*128 + (t & 7)*16;
      float4 m0 = *(const float4*)(mw),   m1 = *(const float4*)(mw+4);
      float4 m2 = *(const float4*)(mw+8), m3 = *(const float4*)(mw+12);
      float s1 = m0.x+m0.y+m0.z+m0.w + m1.x+m1.y+m1.z+m1.w
               + m2.x+m2.y+m2.z+m2.w + m3.x+m3.y+m3.z+m3.w;
      float s2 = m0.x*m0.x+m0.y*m0.y+m0.z*m0.z+m0.w*m0.w
               + m1.x*m1.x+m1.y*m1.y+m1.z*m1.z+m1.w*m1.w
               + m2.x*m2.x+m2.y*m2.y+m2.z*m2.z+m2.w*m2.w
               + m3.x*m3.x+m3.y*m3.y+m3.z*m3.z+m3.w*m3.w;
      #pragma unroll
      for (int m = 1; m < 8; m <<= 1){ s1 += __shfl_xor(s1, m, 64); s2 += __shfl_xor(s2, m, 64); }
      if ((t & 7) == 0) SM[w] = make_float2(s1, s2);
      unsigned* dst = mbf + w*64 + (t & 7)*8;
      dst[0] = packbf(m0.x,m0.y); dst[1] = packbf(m0.z,m0.w);
      dst[2] = packbf(m1.x,m1.y); dst[3] = packbf(m1.z,m1.w);
      dst[4] = packbf(m2.x,m2.y); dst[5] = packbf(m2.z,m2.w);
      dst[6] = packbf(m3.x,m3.y); dst[7] = packbf(m3.z,m3.w);
    }
    if (t < 32) partial[b*32 + t] = 0.f;
  }
}

// ---------------------------------------------------------------------------
// work_kernel: UNION of independent scan (blocks 0..159) and logz (160..409).
// scan: one wave per chain, scalar recurrences (unchanged logic).
// logz: B-frags read straight from mbf (L2-resident, no big LDS) -> high occ.
// ---------------------------------------------------------------------------
__global__ __launch_bounds__(256) void work_kernel(
    // scan args
    const unsigned short* __restrict__ Hh, const unsigned short* __restrict__ Lh,
    const unsigned short* __restrict__ Gh, const float2* __restrict__ SM,
    const float* __restrict__ HU0, const float* __restrict__ LU0,
    const float* __restrict__ D0, const float2* __restrict__ S0,
    const float* __restrict__ prefB, const float* __restrict__ rd,
    int* __restrict__ whichOut,
    // logz args
    const unsigned* __restrict__ mbf, const float* __restrict__ vw,
    const float* __restrict__ vb, float* __restrict__ partial)
{
  __shared__ float les[2048];     // logz reduction (8 KB)

  if (blockIdx.x < NCHAIN){
    // ---------------- scan path (1 wave) ----------------
    const int t = threadIdx.x;
    if (t >= 64) return;
    const int c = blockIdx.x, b = c / NS_;
    const int l = t, t0 = l*8;

    float HU[8], LU[8], D[8], prev1[8], bias[8];
    #pragma unroll
    for (int k = 0; k < 8; k += 4){
      float4 h = *(const float4*)(HU0 + b*ST_ + t0 + k);
      float4 u = *(const float4*)(LU0 + b*ST_ + t0 + k);
      float4 d = *(const float4*)(D0  + b*ST_ + t0 + k);
      float4 bb= *(const float4*)(prefB + t0 + k);
      HU[k]=h.x; HU[k+1]=h.y; HU[k+2]=h.z; HU[k+3]=h.w;
      LU[k]=u.x; LU[k+1]=u.y; LU[k+2]=u.z; LU[k+3]=u.w;
      D[k]=d.x;  D[k+1]=d.y;  D[k+2]=d.z;  D[k+3]=d.w;
      bias[k]=bb.x; bias[k+1]=bb.y; bias[k+2]=bb.z; bias[k+3]=bb.w;
    }
    #pragma unroll
    for (int k = 0; k < 8; ++k) prev1[k] = 0.f;
    float2 s0 = S0[b];
    float S1 = s0.x, S2 = s0.y;
    float rdreg = (l < T_) ? rd[l*(B_*NS_) + c] : 0.f;

    for (int st = 0; st < T_; ++st){
      const float mean = S1 * (1.f/128.f);
      const float var  = (S2 - 128.f*mean*mean) * (1.f/127.f);
      const float sc   = 0.113f / (1e-5f + sqrtf(var));

      float cum[8]; float run = 0.f;
      #pragma unroll
      for (int k = 0; k < 8; ++k){
        float pref = fmaf(sc, HU[k], prev1[k] + bias[k]);
        run += __expf(pref);
        cum[k] = run;
      }
      float incl = run;
      DPPADD(incl, 0x111, 0xf)
      DPPADD(incl, 0x112, 0xf)
      DPPADD(incl, 0x114, 0xf)
      DPPADD(incl, 0x118, 0xf)
      DPPADD(incl, 0x142, 0xa)
      DPPADD(incl, 0x143, 0xc)
      const float total  = readlane_f(incl, 63);
      const float target = readlane_f(rdreg, st) * total;

      const bool cond = target < incl;
      const unsigned long long bal = __ballot(cond);
      const float excl = incl - run;
      int kw = 7; float dcand = D[7];
      #pragma unroll
      for (int k = 6; k >= 0; --k){
        bool ck = target < excl + cum[k];
        kw = ck ? k : kw;
        dcand = ck ? D[k] : dcand;
      }
      int which; float dW;
      if (bal){
        const int wlane = __ffsll(bal) - 1;
        which = __builtin_amdgcn_readlane(t0 + kw, wlane);
        dW    = readlane_f(dcand, wlane);
      } else {
        which = 0;
        dW    = readlane_f(D[0], 0);
      }
      if (l == 0) whichOut[c*T_ + st] = which;

      const int rb = which*ST_ + t0;
      const uint4 hq = *(const uint4*)(Hh + rb);
      const uint4 lq = *(const uint4*)(Lh + rb);
      const uint4 gq = *(const uint4*)(Gh + rb);
      const float2 sm = SM[which];
      const unsigned ha[4] = {hq.x, hq.y, hq.z, hq.w};
      const unsigned la[4] = {lq.x, lq.y, lq.z, lq.w};
      const unsigned ga[4] = {gq.x, gq.y, gq.z, gq.w};
      #pragma unroll
      for (int k = 0; k < 8; ++k){
        const float Hk = h2f(ha[k>>1], k&1);
        const float Lk = h2f(la[k>>1], k&1);
        const float Gk = h2f(ga[k>>1], k&1);
        const float p1 = sc * LU[k];
        HU[k] = fmaf(sc, HU[k], Hk);
        LU[k] = p1 + Lk;
        D[k]  = fmaf(sc, D[k], Gk);
        prev1[k] = p1;
      }
      S1 = fmaf(sc, S1, sm.x);
      S2 = fmaf(sc*sc, S2, fmaf(2.f*sc, dW, sm.y));
    }
  } else {
    // ---------------- logz path ----------------
    const int t = threadIdx.x, lane = t & 63, wv = t >> 6;
    const int lblk = blockIdx.x - NCHAIN;

    const int vbase = lblk*128 + wv*32;
    short8 afr[2][4];
    float vbr[2][4];
    #pragma unroll
    for (int vt = 0; vt < 2; ++vt){
      const int vr = vbase + vt*16 + (lane & 15);
      const float* wp = vw + vr*D_ + (lane >> 4)*8;
      #pragma unroll
      for (int kk = 0; kk < 4; ++kk){
        float4 f0 = *(const float4*)(wp + kk*32);
        float4 f1 = *(const float4*)(wp + kk*32 + 4);
        short8 a;
        a[0]=(short)f2bf(f0.x); a[1]=(short)f2bf(f0.y);
        a[2]=(short)f2bf(f0.z); a[3]=(short)f2bf(f0.w);
        a[4]=(short)f2bf(f1.x); a[5]=(short)f2bf(f1.y);
        a[6]=(short)f2bf(f1.z); a[7]=(short)f2bf(f1.w);
        afr[vt][kk] = a;
      }
      #pragma unroll
      for (int r = 0; r < 4; ++r)
        vbr[vt][r] = vb[vbase + vt*16 + (lane >> 4)*4 + r];
    }

    const char* mb = (const char*)mbf;
    float esl[32];
    #pragma unroll
    for (int s = 0; s < 32; ++s) esl[s] = 0.f;

    #pragma unroll 4
    for (int s = 0; s < 32; ++s){
      short8 bfr[4];
      #pragma unroll
      for (int kk = 0; kk < 4; ++kk){
        const int row = s*16 + (lane & 15);
        bfr[kk] = *(const short8*)(mb + row*256 + (lane >> 4)*16 + kk*64);
      }
      #pragma unroll
      for (int vt = 0; vt < 2; ++vt){
        f32x4 acc = {0.f,0.f,0.f,0.f};
        #pragma unroll
        for (int kk = 0; kk < 4; ++kk)
          acc = __builtin_amdgcn_mfma_f32_16x16x32_bf16(afr[vt][kk], bfr[kk], acc, 0, 0, 0);
        #pragma unroll
        for (int r = 0; r < 4; ++r)
          esl[s] += __expf(acc[r] + vbr[vt][r]);
      }
    }
    #pragma unroll
    for (int s = 0; s < 32; ++s){
      esl[s] += __shfl_xor(esl[s], 16, 64);
      esl[s] += __shfl_xor(esl[s], 32, 64);
    }
    if (lane < 16){
      #pragma unroll
      for (int s = 0; s < 32; ++s) les[wv*512 + s*16 + lane] = esl[s];
    }
    __syncthreads();
    #pragma unroll
    for (int i = 0; i < 2; ++i){
      const int st = t + i*256;
      atomicAdd(&partial[st], les[st] + les[512+st] + les[1024+st] + les[1536+st]);
    }
  }
}

// ---------------------------------------------------------------------------
// dots_kernel: out[b,t] = (Sum_s move[w_s]).vw[y]/NS + vb[y] - Sum_s log(partial[w_s])/NS
// One wave per (b,t) pair: 128 blocks x 256 thr.
// ---------------------------------------------------------------------------
__global__ __launch_bounds__(256) void dots_kernel(
    const int* __restrict__ whichIn, const int* __restrict__ y,
    const float* __restrict__ move, const float* __restrict__ vw,
    const float* __restrict__ vb, const float* __restrict__ partial,
    float* __restrict__ out)
{
  const int p = blockIdx.x*4 + (threadIdx.x >> 6);   // 0..511
  const int lane = threadIdx.x & 63;
  const int b = p >> 5, st = p & 31;

  int w10 = 0; float ls = 0.f;
  if (lane < NS_){
    w10 = whichIn[(b*NS_ + lane)*T_ + st];
    ls  = __logf(partial[w10]);
  }
  #pragma unroll
  for (int m = 1; m < 16; m <<= 1) ls += __shfl_xor(ls, m, 64);

  float mv0 = 0.f, mv1 = 0.f;
  #pragma unroll
  for (int s = 0; s < NS_; ++s){
    const int ws = __builtin_amdgcn_readlane(w10, s);
    mv0 += move[ws*D_ + lane];
    mv1 += move[ws*D_ + 64 + lane];
  }
  const int yr = y[b*T_ + st];
  float pacc = mv0*vw[yr*D_ + lane] + mv1*vw[yr*D_ + 64 + lane];
  #pragma unroll
  for (int m = 1; m < 64; m <<= 1) pacc += __shfl_xor(pacc, m, 64);
  if (lane == 0) out[b*T_ + st] = (pacc - ls) * (1.f/NS_) + vb[yr];
}

extern "C" void kernel_launch(void* const* d_in, const int* in_sizes, int n_in,
                              void* d_out, int out_size, void* d_ws, size_t ws_size,
                              hipStream_t stream)
{
  const int*   zi     = (const int*)d_in[0];
  const int*   y      = (const int*)d_in[1];
  const float* rd     = (const float*)d_in[2];
  const float* latent = (const float*)d_in[3];
  const float* prefW  = (const float*)d_in[4];
  const float* prefB  = (const float*)d_in[5];
  const float* move   = (const float*)d_in[6];
  const float* vw     = (const float*)d_in[7];
  const float* vb     = (const float*)d_in[8];
  float* out = (float*)d_out;

  char* ws = (char*)d_ws;
  unsigned short* Hh = (unsigned short*)(ws);           // 512 KB
  unsigned short* Lh = (unsigned short*)(ws + 524288);  // 512 KB
  unsigned short* Gh = (unsigned short*)(ws + 1048576); // 512 KB
  float2* SM    = (float2*)(ws + 1572864);              // 4 KB
  float*  HU0   = (float*)(ws + 1576960);               // 32 KB
  float*  LU0   = (float*)(ws + 1609728);               // 32 KB
  float*  D0    = (float*)(ws + 1642496);               // 32 KB
  float2* S0    = (float2*)(ws + 1675264);              // 128 B
  float*  partial = (float*)(ws + 1675392);             // 2 KB
  int*    which = (int*)(ws + 1677440);                 // 20 KB
  unsigned* mbf = (unsigned*)(ws + 1697920);            // 128 KB (bf16 move)

  hipLaunchKernelGGL(prep_kernel, dim3(64), dim3(256), 0, stream,
                     zi, latent, prefW, move, Hh, Lh, Gh,
                     HU0, LU0, D0, S0, SM, mbf, partial);
  hipLaunchKernelGGL(work_kernel, dim3(NCHAIN + 250), dim3(256), 0, stream,
                     Hh, Lh, Gh, SM, HU0, LU0, D0, S0, prefB, rd, which,
                     mbf, vw, vb, partial);
  hipLaunchKernelGGL(dots_kernel, dim3(128), dim3(256), 0, stream,
                     which, y, move, vw, vb, partial, out);
}